// Round 4
// baseline (494.065 us; speedup 1.0000x reference)
//
#include <hip/hip_runtime.h>

#define N_NODES 100000
#define N_EDGES 1600000
#define C_DIM   128
#define R_TYPES 7
#define T_TYPES 4
#define SEGS    (N_NODES * R_TYPES)          // 700000 (dst,rel) segments
#define NB_E    (N_EDGES / 256)              // 6250 (E % 256 == 0)
#define NB_N    ((N_NODES + 255) / 256)      // 391 node blocks (also dst-scan blocks)
#define XP_ROWS 100096                       // N padded to 128-row tiles (782 tiles)
#define DST_PART 12500                       // N / 8 (exact)

// ---- workspace layout (bytes) ----
#define OFF_CNTI   0ull                       // int  cnti[SEGS]            2.80 MB
#define OFF_INV    2800000ull                 // f32  inv[SEGS]             2.80 MB
#define OFF_DOFF   5600000ull                 // int  dst_off[N+1]          0.40 MB
#define OFF_CURS   6000004ull                 // int  cursor[N]             0.40 MB
#define OFF_MISC   6400004ull                 // int  misc[32]
#define OFF_PERM   6400132ull                 // int  perm[PERM_CAP]        0.40 MB
#define PERM_CAP   100288
#define N_PERM_BLOCKS 1567
#define OFF_BLKN   6801284ull                 // int  blk_n[NB_N*8]
#define OFF_BSUM   6813796ull                 // int  bsum[NB_N]
#define OFF_ESRC   6815360ull                 // int  esrc[E] packed r<<20|(r*XP_ROWS+src)
#define OFF_XP     13215360ull                // bf16 xp[XP_ROWS*128] frag     25.6 MB
#define OFF_WF     38839936ull                // bf16 wf[7*128*128] frag        0.23 MB
#define OFF_XWB    39069312ull                // bf16 xwb: full = 7 planes, fallback = 1
#define XWB_PLANE  ((size_t)XP_ROWS * 128)    // elements per relation plane
#define FULL_NEED  218441344ull               // OFF_XWB + 7*25,624,576
#define FB_NEED    64693888ull                // OFF_XWB + 1*25,624,576
// root-linear hi/lo W fragments (8 planes x 16384 bf16 = 256 KB) live in the
// cnti region, which is dead after dst_scan1; cvt_rootw_frag launches after it.
#define OFF_WRF    OFF_CNTI

typedef __attribute__((ext_vector_type(8))) short short8;
typedef __attribute__((ext_vector_type(4))) float f32x4;

__device__ inline unsigned short f2bf(float f) {
    unsigned int u = __float_as_uint(f);
    u += 0x7fffu + ((u >> 16) & 1u);          // RNE
    return (unsigned short)(u >> 16);
}
__device__ inline float bf2f(unsigned int h) { return __uint_as_float(h << 16); }

// ---------------- per-(dst,rel) counts ----------------
__global__ void edge_hist(const int* __restrict__ ei, const int* __restrict__ et,
                          int* __restrict__ cnti) {
    int e = blockIdx.x * 256 + threadIdx.x;
    atomicAdd(&cnti[ei[N_EDGES + e] * R_TYPES + et[e]], 1);   // 700k addrs: low contention
}

__global__ void inv_kernel(const int* __restrict__ cnti, float* __restrict__ inv) {
    int i = blockIdx.x * blockDim.x + threadIdx.x;
    if (i < SEGS) inv[i] = 1.0f / (float)max(cnti[i], 1);
}

// ---------------- dst-CSR: dst_off = exclusive scan of per-dst degree ----------------
__global__ void dst_scan1(const int* __restrict__ cnti, int* __restrict__ dst_off,
                          int* __restrict__ bsum) {
    __shared__ int sbuf[256];
    int tid = threadIdx.x;
    int i = blockIdx.x * 256 + tid;
    int v = 0;
    if (i < N_NODES) {
        #pragma unroll
        for (int r = 0; r < R_TYPES; ++r) v += cnti[i * R_TYPES + r];
    }
    sbuf[tid] = v;
    __syncthreads();
    #pragma unroll
    for (int off = 1; off < 256; off <<= 1) {
        int t = (tid >= off) ? sbuf[tid - off] : 0;
        __syncthreads();
        sbuf[tid] += t;
        __syncthreads();
    }
    int incl = sbuf[tid];
    if (i < N_NODES) dst_off[i] = incl - v;   // exclusive within chunk
    if (tid == 255) bsum[blockIdx.x] = incl;
}

__global__ void seg_scan2(int* __restrict__ bsum, int nb) {   // 1 block
    __shared__ int sbuf[256];
    int tid = threadIdx.x;
    int running = 0;
    for (int c0 = 0; c0 < nb; c0 += 256) {
        int b = c0 + tid;
        int v = (b < nb) ? bsum[b] : 0;
        sbuf[tid] = v;
        __syncthreads();
        #pragma unroll
        for (int off = 1; off < 256; off <<= 1) {
            int t = (tid >= off) ? sbuf[tid - off] : 0;
            __syncthreads();
            sbuf[tid] += t;
            __syncthreads();
        }
        int incl = sbuf[tid];
        int tot = sbuf[255];
        __syncthreads();
        if (b < nb) bsum[b] = running + incl - v;
        running += tot;
    }
}

__global__ void dst_scan3(int* __restrict__ dst_off, int* __restrict__ cursor,
                          const int* __restrict__ bsum) {
    int i = blockIdx.x * 256 + threadIdx.x;
    if (i < N_NODES) {
        int val = dst_off[i] + bsum[blockIdx.x];
        dst_off[i] = val;
        cursor[i] = val;
    }
    if (i == 0) dst_off[N_NODES] = N_EDGES;
}

// XCD-partitioned placement: block b = chunk (b>>3) x partition (b&7).
// Packs the precomputed xwb7 row index (r*XP_ROWS+src, 20 bits) plus r (3 bits)
// so the gather needs no 64-bit multiply per edge.
__global__ void place_edges(const int* __restrict__ ei, const int* __restrict__ et,
                            int* __restrict__ cursor, int* __restrict__ esrc) {
    int p = blockIdx.x & 7;
    int e = (blockIdx.x >> 3) * 256 + threadIdx.x;
    int d = ei[N_EDGES + e];
    if (d / DST_PART != p) return;
    int pos = atomicAdd(&cursor[d], 1);
    int r = et[e];
    esrc[pos] = (r << 20) | (r * XP_ROWS + ei[e]);   // r in [20:23), rowidx in [0:20)
}

// ---------------- node-type bucketing (for root linear) ----------------
__global__ void node_hist(const int* __restrict__ tnt, int* __restrict__ blk_n) {
    __shared__ int h[8];
    int tid = threadIdx.x;
    if (tid < 8) h[tid] = 0;
    __syncthreads();
    int n = blockIdx.x * 256 + tid;
    if (n < N_NODES) atomicAdd(&h[tnt[n]], 1);
    __syncthreads();
    if (tid < T_TYPES) blk_n[blockIdx.x * 8 + tid] = h[tid];
}

__global__ void scan_blocks(int* __restrict__ blk, int nb, int* __restrict__ total) {
    __shared__ int sbuf[256];
    int r = blockIdx.x;
    int tid = threadIdx.x;
    int running = 0;
    for (int c0 = 0; c0 < nb; c0 += 256) {
        int b = c0 + tid;
        int v = (b < nb) ? blk[b * 8 + r] : 0;
        sbuf[tid] = v;
        __syncthreads();
        #pragma unroll
        for (int off = 1; off < 256; off <<= 1) {
            int t = (tid >= off) ? sbuf[tid - off] : 0;
            __syncthreads();
            sbuf[tid] += t;
            __syncthreads();
        }
        int incl = sbuf[tid];
        int chunk_total = sbuf[255];
        __syncthreads();
        if (b < nb) blk[b * 8 + r] = running + incl - v;
        running += chunk_total;
    }
    if (tid == 0) total[r] = running;
}

__global__ void offsets_kernel(int* misc) {
    if (threadIdx.x == 0 && blockIdx.x == 0) {
        int s = 0;
        for (int t = 0; t < T_TYPES; ++t) {
            misc[4 + t] = s;
            s += ((misc[t] + 63) / 64) * 64;
        }
    }
}

__global__ void node_scatter(const int* __restrict__ tnt, const int* __restrict__ misc,
                             const int* __restrict__ blk_n, int* __restrict__ perm) {
    __shared__ int h[8];
    int tid = threadIdx.x;
    if (tid < 8) h[tid] = 0;
    __syncthreads();
    int n = blockIdx.x * 256 + tid;
    if (n < N_NODES) {
        int t = tnt[n];
        int rank = atomicAdd(&h[t], 1);
        perm[misc[4 + t] + blk_n[blockIdx.x * 8 + t] + rank] = n;
    }
}

// ---------------- bf16 fragment-layout conversions ----------------
__global__ void cvt_x_frag(const float* __restrict__ x, unsigned short* __restrict__ xp) {
    int id = blockIdx.x * 256 + threadIdx.x;       // XP_ROWS*16 exact
    int n = id >> 4, ko = id & 15;
    short8 o;
    if (n < N_NODES) {
        const float4* px = (const float4*)(x + (size_t)n * C_DIM + ko * 8);
        float4 a = px[0], b = px[1];
        o[0] = (short)f2bf(a.x); o[1] = (short)f2bf(a.y);
        o[2] = (short)f2bf(a.z); o[3] = (short)f2bf(a.w);
        o[4] = (short)f2bf(b.x); o[5] = (short)f2bf(b.y);
        o[6] = (short)f2bf(b.z); o[7] = (short)f2bf(b.w);
    } else {
        o = (short8)0;
    }
    size_t off = (size_t)(n >> 4) * 2048 + (ko >> 2) * 512 + (ko & 3) * 128 + (n & 15) * 8;
    *(short8*)(xp + off) = o;
}

__global__ void cvt_w_frag(const float* __restrict__ rel_w, unsigned short* __restrict__ wf) {
    int id = blockIdx.x * 256 + threadIdx.x;       // 7*128*16 = 14336 exact
    if (id >= R_TYPES * 128 * 16) return;
    int r = id >> 11, rest = id & 2047;
    int o = rest >> 4, ko = rest & 15;
    const float4* pw = (const float4*)(rel_w + (size_t)r * 16384 + o * 128 + ko * 8);
    float4 a = pw[0], b = pw[1];
    short8 v;
    v[0] = (short)f2bf(a.x); v[1] = (short)f2bf(a.y);
    v[2] = (short)f2bf(a.z); v[3] = (short)f2bf(a.w);
    v[4] = (short)f2bf(b.x); v[5] = (short)f2bf(b.y);
    v[6] = (short)f2bf(b.z); v[7] = (short)f2bf(b.w);
    size_t off = (size_t)r * 16384 + (o >> 4) * 2048 + (ko >> 2) * 512 + (ko & 3) * 128 + (o & 15) * 8;
    *(short8*)(wf + off) = v;
}

// root_w -> MFMA B-frag layout, hi plane [0..3] and lo plane [4..7] (hi/lo bf16 split)
__global__ void cvt_rootw_frag(const float* __restrict__ root_w, unsigned short* __restrict__ wrf) {
    int id = blockIdx.x * 256 + threadIdx.x;       // 4*128*16 = 8192 exact
    if (id >= T_TYPES * 128 * 16) return;
    int t = id >> 11, rest = id & 2047;
    int o = rest >> 4, ko = rest & 15;
    const float4* pw = (const float4*)(root_w + (size_t)t * 16384 + o * 128 + ko * 8);
    float4 a = pw[0], b = pw[1];
    float v[8] = {a.x, a.y, a.z, a.w, b.x, b.y, b.z, b.w};
    short8 hi, lo;
    #pragma unroll
    for (int j = 0; j < 8; ++j) {
        unsigned short h = f2bf(v[j]);
        hi[j] = (short)h;
        lo[j] = (short)f2bf(v[j] - bf2f(h));
    }
    size_t off = (size_t)t * 16384 + (o >> 4) * 2048 + (ko >> 2) * 512 + (ko & 3) * 128 + (o & 15) * 8;
    *(short8*)(wrf + off) = hi;
    *(short8*)(wrf + (size_t)T_TYPES * 16384 + off) = lo;
}

// ---------------- fused MFMA GEMM, all 7 relations in one dispatch ----------------
// Block owns 128 rows; A fragments loaded ONCE, reused for all 7 weight sets.
__launch_bounds__(256)
__global__ void xw_gemm_all(const unsigned short* __restrict__ xp,
                            const unsigned short* __restrict__ wf,
                            unsigned short* __restrict__ xwb7) {
    int wave = threadIdx.x >> 6, lane = threadIdx.x & 63;
    int m0 = blockIdx.x * 128;

    short8 a[4][2];
    #pragma unroll
    for (int kb = 0; kb < 4; ++kb)
        #pragma unroll
        for (int rt = 0; rt < 2; ++rt) {
            size_t rtile = (size_t)blockIdx.x * 8 + wave * 2 + rt;
            a[kb][rt] = *(const short8*)(xp + rtile * 2048 + kb * 512 + lane * 8);
        }

    int col = lane & 15, rq = (lane >> 4) * 4;     // C/D: col=lane&15,row=(lane>>4)*4+i
    for (int r = 0; r < R_TYPES; ++r) {
        const unsigned short* wr = wf + (size_t)r * 16384;
        unsigned short* xwb = xwb7 + (size_t)r * XWB_PLANE;
        #pragma unroll
        for (int ct = 0; ct < 8; ++ct) {
            f32x4 acc0 = (f32x4)0.0f, acc1 = (f32x4)0.0f;
            #pragma unroll
            for (int kb = 0; kb < 4; ++kb) {
                short8 b = *(const short8*)(wr + (size_t)ct * 2048 + kb * 512 + lane * 8);
                acc0 = __builtin_amdgcn_mfma_f32_16x16x32_bf16(a[kb][0], b, acc0, 0, 0, 0);
                acc1 = __builtin_amdgcn_mfma_f32_16x16x32_bf16(a[kb][1], b, acc1, 0, 0, 0);
            }
            #pragma unroll
            for (int i = 0; i < 4; ++i) {
                int n0 = m0 + wave * 32 + rq + i;
                if (n0 < N_NODES)
                    xwb[(size_t)n0 * C_DIM + ct * 16 + col] = f2bf(acc0[i]);
                int n1 = n0 + 16;
                if (n1 < N_NODES)
                    xwb[(size_t)n1 * C_DIM + ct * 16 + col] = f2bf(acc1[i]);
            }
        }
    }
}

// fallback per-relation GEMM (single plane)
__launch_bounds__(256)
__global__ void xw_gemm_mfma(const unsigned short* __restrict__ xp,
                             const unsigned short* __restrict__ wf,
                             unsigned short* __restrict__ xwb, int r) {
    int wave = threadIdx.x >> 6, lane = threadIdx.x & 63;
    int m0 = blockIdx.x * 128;
    const unsigned short* wr = wf + (size_t)r * 16384;

    short8 a[4][2];
    #pragma unroll
    for (int kb = 0; kb < 4; ++kb)
        #pragma unroll
        for (int rt = 0; rt < 2; ++rt) {
            size_t rtile = (size_t)blockIdx.x * 8 + wave * 2 + rt;
            a[kb][rt] = *(const short8*)(xp + rtile * 2048 + kb * 512 + lane * 8);
        }

    int col = lane & 15, rq = (lane >> 4) * 4;
    #pragma unroll
    for (int ct = 0; ct < 8; ++ct) {
        f32x4 acc0 = (f32x4)0.0f, acc1 = (f32x4)0.0f;
        #pragma unroll
        for (int kb = 0; kb < 4; ++kb) {
            short8 b = *(const short8*)(wr + (size_t)ct * 2048 + kb * 512 + lane * 8);
            acc0 = __builtin_amdgcn_mfma_f32_16x16x32_bf16(a[kb][0], b, acc0, 0, 0, 0);
            acc1 = __builtin_amdgcn_mfma_f32_16x16x32_bf16(a[kb][1], b, acc1, 0, 0, 0);
        }
        #pragma unroll
        for (int i = 0; i < 4; ++i) {
            int n0 = m0 + wave * 32 + rq + i;
            if (n0 < N_NODES)
                xwb[(size_t)n0 * C_DIM + ct * 16 + col] = f2bf(acc0[i]);
            int n1 = n0 + 16;
            if (n1 < N_NODES)
                xwb[(size_t)n1 * C_DIM + ct * 16 + col] = f2bf(acc1[i]);
        }
    }
}

// ---------------- fused gather: out[d] = sum over d's edges of xwb7[r][src]*inv[d*7+r]
// Quarter-lane layout: 16 lanes per edge row (uint4 = 16B/lane), 4 edges per load
// instruction, x2 unroll -> 8 independent 256B rows in flight per wave-iteration.
// esrc for the NEXT iteration is prefetched before the current accumulate so the
// index-load latency overlaps the row loads. Reduce: shfl_xor 16 + 32; 16 lanes
// write the 512B output row.
__global__ void gather_fused(const int* __restrict__ dst_off, const int* __restrict__ esrc,
                             const float* __restrict__ inv,
                             const unsigned short* __restrict__ xwb7,
                             float* __restrict__ out) {
    int wave = threadIdx.x >> 6, lane = threadIdx.x & 63;
    int d = blockIdx.x * 4 + wave;
    if (d >= N_NODES) return;
    int o0 = dst_off[d], o1 = dst_off[d + 1];
    int q = lane >> 4;               // quarter: which edge of a 4-group
    int l16 = lane & 15;
    const float* invd = inv + d * R_TYPES;
    float acc[8];
    #pragma unroll
    for (int j = 0; j < 8; ++j) acc[j] = 0.f;

    int e = o0;
    int pkA = 0, pkB = 0;
    bool run = (e + 8 <= o1);
    if (run) { pkA = esrc[e + q]; pkB = esrc[e + 4 + q]; }
    while (run) {
        uint4 rA = *(const uint4*)(xwb7 + (size_t)(pkA & 0xFFFFF) * C_DIM + l16 * 8);
        uint4 rB = *(const uint4*)(xwb7 + (size_t)(pkB & 0xFFFFF) * C_DIM + l16 * 8);
        float sA = invd[pkA >> 20];
        float sB = invd[pkB >> 20];
        e += 8;
        run = (e + 8 <= o1);
        if (run) { pkA = esrc[e + q]; pkB = esrc[e + 4 + q]; }   // prefetch next iter
        acc[0] += bf2f(rA.x & 0xffffu) * sA;  acc[1] += bf2f(rA.x >> 16) * sA;
        acc[2] += bf2f(rA.y & 0xffffu) * sA;  acc[3] += bf2f(rA.y >> 16) * sA;
        acc[4] += bf2f(rA.z & 0xffffu) * sA;  acc[5] += bf2f(rA.z >> 16) * sA;
        acc[6] += bf2f(rA.w & 0xffffu) * sA;  acc[7] += bf2f(rA.w >> 16) * sA;
        acc[0] += bf2f(rB.x & 0xffffu) * sB;  acc[1] += bf2f(rB.x >> 16) * sB;
        acc[2] += bf2f(rB.y & 0xffffu) * sB;  acc[3] += bf2f(rB.y >> 16) * sB;
        acc[4] += bf2f(rB.z & 0xffffu) * sB;  acc[5] += bf2f(rB.z >> 16) * sB;
        acc[6] += bf2f(rB.w & 0xffffu) * sB;  acc[7] += bf2f(rB.w >> 16) * sB;
    }
    for (; e < o1; e += 4) {                 // tail: 1-7 edges, 1-2 groups of 4
        int idx = e + q;
        bool valid = idx < o1;
        int pk = esrc[valid ? idx : e];      // e < o1 here: safe clamp
        uint4 rw = *(const uint4*)(xwb7 + (size_t)(pk & 0xFFFFF) * C_DIM + l16 * 8);
        float s = valid ? invd[pk >> 20] : 0.0f;
        acc[0] += bf2f(rw.x & 0xffffu) * s;  acc[1] += bf2f(rw.x >> 16) * s;
        acc[2] += bf2f(rw.y & 0xffffu) * s;  acc[3] += bf2f(rw.y >> 16) * s;
        acc[4] += bf2f(rw.z & 0xffffu) * s;  acc[5] += bf2f(rw.z >> 16) * s;
        acc[6] += bf2f(rw.w & 0xffffu) * s;  acc[7] += bf2f(rw.w >> 16) * s;
    }

    #pragma unroll
    for (int j = 0; j < 8; ++j) {
        acc[j] += __shfl_xor(acc[j], 16);
        acc[j] += __shfl_xor(acc[j], 32);
    }
    if (lane < 16) {
        float4* po = (float4*)(out + (size_t)d * C_DIM + l16 * 8);
        po[0] = make_float4(acc[0], acc[1], acc[2], acc[3]);
        po[1] = make_float4(acc[4], acc[5], acc[6], acc[7]);   // full overwrite
    }
}

// ---------------- fallback gather (single xwb plane, filter by r, RMW out) -----
__global__ void gather_rel_f(const int* __restrict__ dst_off, const int* __restrict__ esrc,
                             const float* __restrict__ inv,
                             const unsigned short* __restrict__ xwb,
                             float* __restrict__ out, int rf) {
    int wave = threadIdx.x >> 6, lane = threadIdx.x & 63;
    int d = blockIdx.x * 4 + wave;
    if (d >= N_NODES) return;
    int o0 = dst_off[d], o1 = dst_off[d + 1];
    float ax = 0.0f, ay = 0.0f;
    bool any = false;
    for (int e = o0; e < o1; ++e) {
        int pk = esrc[e];
        if ((pk >> 20) != rf) continue;
        any = true;
        int src = (pk & 0xFFFFF) - rf * XP_ROWS;
        unsigned int row = *(const unsigned int*)(xwb + (size_t)src * C_DIM + lane * 2);
        ax += bf2f(row & 0xffffu);
        ay += bf2f(row >> 16);
    }
    if (!any) return;
    float sc = inv[d * R_TYPES + rf];
    float2* po = (float2*)(out + (size_t)d * C_DIM) + lane;
    float2 v = *po;
    v.x += ax * sc;
    v.y += ay * sc;
    *po = v;
}

// ---------------- root linear via MFMA, hi/lo bf16 split (fp32-level accuracy) ----
// Per block: 64 type-uniform nodes (perm bucket), 4 waves x 16 rows each.
// No LDS tiles, no k-loop barriers: A frags from x (hi/lo computed in-reg),
// B frags pre-converted (wrf). 3 MFMA passes: ah*bh + al*bh + ah*bl.
// Epilogue RMWs out in coalesced 64B quarter-wave groups, adds bias.
__launch_bounds__(256)
__global__ void root_mfma(const float* __restrict__ x, const unsigned short* __restrict__ wrf,
                          const float* __restrict__ root_b, const int* __restrict__ tnt,
                          const int* __restrict__ perm, float* __restrict__ out) {
    __shared__ int pidx[64];
    int tid = threadIdx.x;
    int wave = tid >> 6, lane = tid & 63;
    if (tid < 64) pidx[tid] = perm[blockIdx.x * 64 + tid];
    __syncthreads();
    if (pidx[0] < 0) return;
    int t = tnt[pidx[0]];

    int node = pidx[wave * 16 + (lane & 15)];      // A row; -1 padding contributes 0
    int k0 = (lane >> 4) * 8;
    short8 ah[4], al[4];
    #pragma unroll
    for (int kb = 0; kb < 4; ++kb) {
        float v[8];
        if (node >= 0) {
            const float4* px = (const float4*)(x + (size_t)node * C_DIM + kb * 32 + k0);
            float4 p0 = px[0], p1 = px[1];
            v[0] = p0.x; v[1] = p0.y; v[2] = p0.z; v[3] = p0.w;
            v[4] = p1.x; v[5] = p1.y; v[6] = p1.z; v[7] = p1.w;
        } else {
            #pragma unroll
            for (int j = 0; j < 8; ++j) v[j] = 0.0f;
        }
        #pragma unroll
        for (int j = 0; j < 8; ++j) {
            unsigned short h = f2bf(v[j]);
            ah[kb][j] = (short)h;
            al[kb][j] = (short)f2bf(v[j] - bf2f(h));
        }
    }

    const unsigned short* wh = wrf + (size_t)t * 16384;
    const unsigned short* wl = wrf + (size_t)(T_TYPES + t) * 16384;
    int col = lane & 15, rq = (lane >> 4) * 4;
    #pragma unroll
    for (int ct = 0; ct < 8; ++ct) {
        f32x4 acc = (f32x4)0.0f;
        #pragma unroll
        for (int kb = 0; kb < 4; ++kb) {
            short8 bh = *(const short8*)(wh + ct * 2048 + kb * 512 + lane * 8);
            short8 bl = *(const short8*)(wl + ct * 2048 + kb * 512 + lane * 8);
            acc = __builtin_amdgcn_mfma_f32_16x16x32_bf16(ah[kb], bh, acc, 0, 0, 0);
            acc = __builtin_amdgcn_mfma_f32_16x16x32_bf16(al[kb], bh, acc, 0, 0, 0);
            acc = __builtin_amdgcn_mfma_f32_16x16x32_bf16(ah[kb], bl, acc, 0, 0, 0);
        }
        float bias = root_b[t * 128 + ct * 16 + col];
        #pragma unroll
        for (int i = 0; i < 4; ++i) {
            int nr = pidx[wave * 16 + rq + i];
            if (nr >= 0) {
                float* po = out + (size_t)nr * C_DIM + ct * 16 + col;
                *po += acc[i] + bias;
            }
        }
    }
}

extern "C" void kernel_launch(void* const* d_in, const int* in_sizes, int n_in,
                              void* d_out, int out_size, void* d_ws, size_t ws_size,
                              hipStream_t stream) {
    const float* x      = (const float*)d_in[0];
    const int*   ei     = (const int*)d_in[1];
    const int*   et     = (const int*)d_in[2];
    const int*   tnt    = (const int*)d_in[3];
    const float* rel_w  = (const float*)d_in[4];
    const float* root_w = (const float*)d_in[5];
    const float* root_b = (const float*)d_in[6];
    float* out = (float*)d_out;

    char* ws = (char*)d_ws;
    int*   cnti    = (int*)(ws + OFF_CNTI);
    float* inv     = (float*)(ws + OFF_INV);
    int*   dst_off = (int*)(ws + OFF_DOFF);
    int*   cursor  = (int*)(ws + OFF_CURS);
    int*   misc    = (int*)(ws + OFF_MISC);
    int*   perm    = (int*)(ws + OFF_PERM);
    int*   blk_n   = (int*)(ws + OFF_BLKN);
    int*   bsum    = (int*)(ws + OFF_BSUM);
    int*   esrc    = (int*)(ws + OFF_ESRC);
    unsigned short* xp  = (unsigned short*)(ws + OFF_XP);
    unsigned short* wf  = (unsigned short*)(ws + OFF_WF);
    unsigned short* xwb = (unsigned short*)(ws + OFF_XWB);
    unsigned short* wrf = (unsigned short*)(ws + OFF_WRF);   // overlays cnti (dead after dst_scan1)

    const bool full = (ws_size >= FULL_NEED);   // constant across calls: graph-safe

    hipMemsetAsync(ws + OFF_CNTI, 0, SEGS * sizeof(int), stream);
    hipMemsetAsync(ws + OFF_MISC, 0, 32 * sizeof(int), stream);
    hipMemsetAsync(ws + OFF_PERM, 0xFF, (size_t)PERM_CAP * sizeof(int), stream);
    if (!full)
        hipMemsetAsync(d_out, 0, (size_t)out_size * sizeof(float), stream);

    // dst-CSR sort of edges
    edge_hist  <<<NB_E, 256, 0, stream>>>(ei, et, cnti);
    inv_kernel <<<(SEGS + 255) / 256, 256, 0, stream>>>(cnti, inv);
    dst_scan1  <<<NB_N, 256, 0, stream>>>(cnti, dst_off, bsum);
    seg_scan2  <<<1, 256, 0, stream>>>(bsum, NB_N);
    dst_scan3  <<<NB_N, 256, 0, stream>>>(dst_off, cursor, bsum);
    place_edges<<<NB_E * 8, 256, 0, stream>>>(ei, et, cursor, esrc);

    // root W hi/lo fragment conversion (into cnti region — cnti dead after dst_scan1)
    cvt_rootw_frag<<<32, 256, 0, stream>>>(root_w, wrf);

    // node-type buckets for root linear
    node_hist  <<<NB_N, 256, 0, stream>>>(tnt, blk_n);
    scan_blocks<<<T_TYPES, 256, 0, stream>>>(blk_n, NB_N, misc + 0);
    offsets_kernel<<<1, 64, 0, stream>>>(misc);
    node_scatter<<<NB_N, 256, 0, stream>>>(tnt, misc, blk_n, perm);

    // bf16 fragment-layout conversions
    cvt_x_frag<<<(XP_ROWS * 16) / 256, 256, 0, stream>>>(x, xp);
    cvt_w_frag<<<56, 256, 0, stream>>>(rel_w, wf);

    if (full) {
        xw_gemm_all <<<XP_ROWS / 128, 256, 0, stream>>>(xp, wf, xwb);
        gather_fused<<<(N_NODES + 3) / 4, 256, 0, stream>>>(dst_off, esrc, inv, xwb, out);
    } else {
        for (int r = 0; r < R_TYPES; ++r) {
            xw_gemm_mfma<<<XP_ROWS / 128, 256, 0, stream>>>(xp, wf, xwb, r);
            gather_rel_f<<<(N_NODES + 3) / 4, 256, 0, stream>>>(dst_off, esrc, inv, xwb, out, r);
        }
    }
    root_mfma<<<N_PERM_BLOCKS, 256, 0, stream>>>(x, wrf, root_b, tnt, perm, out);
}

// Round 5
// 470.251 us; speedup vs baseline: 1.0506x; 1.0506x over previous
//
#include <hip/hip_runtime.h>

#define N_NODES 100000
#define N_EDGES 1600000
#define C_DIM   128
#define R_TYPES 7
#define T_TYPES 4
#define SEGS    (N_NODES * R_TYPES)          // 700000 (dst,rel) segments
#define NB_E    (N_EDGES / 256)              // 6250 (E % 256 == 0)
#define NB_N    ((N_NODES + 255) / 256)      // 391 node blocks (also dst-scan blocks)
#define XP_ROWS 100096                       // N padded to 128-row tiles (782 tiles)
#define DST_PART 12500                       // N / 8 (exact)
#define NB_ROOT ((N_NODES + 63) / 64)        // 1563 root blocks (64 nodes each)

// ---- workspace layout (bytes) ----
#define OFF_CNTI   0ull                       // int  cnti[SEGS]            2.80 MB
#define OFF_INV    2800000ull                 // f32  inv[SEGS]             2.80 MB
#define OFF_DOFF   5600000ull                 // int  dst_off[N+1]          0.40 MB
#define OFF_CURS   6000004ull                 // int  cursor[N]             0.40 MB
#define OFF_MISC   6400004ull                 // int  misc[32]   (unused now)
#define OFF_PERM   6400132ull                 // REUSED: bf16 wrf[8*16384] = 256 KB
#define PERM_CAP   100288
#define OFF_BLKN   6801284ull                 // (unused now)
#define OFF_BSUM   6813796ull                 // int  bsum[NB_N]
#define OFF_ESRC   6815360ull                 // int  esrc[E] packed r<<20|(r*XP_ROWS+src)
#define OFF_XP     13215360ull                // bf16 xp[XP_ROWS*128] frag     25.6 MB
#define OFF_WF     38839936ull                // bf16 wf[7*128*128] frag        0.23 MB
#define OFF_XWB    39069312ull                // bf16 xwb: full = 7 planes, fallback = 1
#define XWB_PLANE  ((size_t)XP_ROWS * 128)    // elements per relation plane
#define FULL_NEED  218441344ull               // OFF_XWB + 7*25,624,576
#define FB_NEED    64693888ull                // OFF_XWB + 1*25,624,576
#define OFF_WRF    OFF_PERM                   // root hi/lo W frags (256 KB)

typedef __attribute__((ext_vector_type(8))) short short8;
typedef __attribute__((ext_vector_type(4))) float f32x4;

__device__ inline unsigned short f2bf(float f) {
    unsigned int u = __float_as_uint(f);
    u += 0x7fffu + ((u >> 16) & 1u);          // RNE
    return (unsigned short)(u >> 16);
}
__device__ inline float bf2f(unsigned int h) { return __uint_as_float(h << 16); }

// ---------------- per-(dst,rel) counts ----------------
__global__ void edge_hist(const int* __restrict__ ei, const int* __restrict__ et,
                          int* __restrict__ cnti) {
    int e = blockIdx.x * 256 + threadIdx.x;
    atomicAdd(&cnti[ei[N_EDGES + e] * R_TYPES + et[e]], 1);   // 700k addrs: low contention
}

__global__ void inv_kernel(const int* __restrict__ cnti, float* __restrict__ inv) {
    int i = blockIdx.x * blockDim.x + threadIdx.x;
    if (i < SEGS) inv[i] = 1.0f / (float)max(cnti[i], 1);
}

// ---------------- dst-CSR: dst_off = exclusive scan of per-dst degree ----------------
__global__ void dst_scan1(const int* __restrict__ cnti, int* __restrict__ dst_off,
                          int* __restrict__ bsum) {
    __shared__ int sbuf[256];
    int tid = threadIdx.x;
    int i = blockIdx.x * 256 + tid;
    int v = 0;
    if (i < N_NODES) {
        #pragma unroll
        for (int r = 0; r < R_TYPES; ++r) v += cnti[i * R_TYPES + r];
    }
    sbuf[tid] = v;
    __syncthreads();
    #pragma unroll
    for (int off = 1; off < 256; off <<= 1) {
        int t = (tid >= off) ? sbuf[tid - off] : 0;
        __syncthreads();
        sbuf[tid] += t;
        __syncthreads();
    }
    int incl = sbuf[tid];
    if (i < N_NODES) dst_off[i] = incl - v;   // exclusive within chunk
    if (tid == 255) bsum[blockIdx.x] = incl;
}

__global__ void seg_scan2(int* __restrict__ bsum, int nb) {   // 1 block
    __shared__ int sbuf[256];
    int tid = threadIdx.x;
    int running = 0;
    for (int c0 = 0; c0 < nb; c0 += 256) {
        int b = c0 + tid;
        int v = (b < nb) ? bsum[b] : 0;
        sbuf[tid] = v;
        __syncthreads();
        #pragma unroll
        for (int off = 1; off < 256; off <<= 1) {
            int t = (tid >= off) ? sbuf[tid - off] : 0;
            __syncthreads();
            sbuf[tid] += t;
            __syncthreads();
        }
        int incl = sbuf[tid];
        int tot = sbuf[255];
        __syncthreads();
        if (b < nb) bsum[b] = running + incl - v;
        running += tot;
    }
}

__global__ void dst_scan3(int* __restrict__ dst_off, int* __restrict__ cursor,
                          const int* __restrict__ bsum) {
    int i = blockIdx.x * 256 + threadIdx.x;
    if (i < N_NODES) {
        int val = dst_off[i] + bsum[blockIdx.x];
        dst_off[i] = val;
        cursor[i] = val;
    }
    if (i == 0) dst_off[N_NODES] = N_EDGES;
}

// XCD-partitioned placement: block b = chunk (b>>3) x partition (b&7).
__global__ void place_edges(const int* __restrict__ ei, const int* __restrict__ et,
                            int* __restrict__ cursor, int* __restrict__ esrc) {
    int p = blockIdx.x & 7;
    int e = (blockIdx.x >> 3) * 256 + threadIdx.x;
    int d = ei[N_EDGES + e];
    if (d / DST_PART != p) return;
    int pos = atomicAdd(&cursor[d], 1);
    int r = et[e];
    esrc[pos] = (r << 20) | (r * XP_ROWS + ei[e]);   // r in [20:23), rowidx in [0:20)
}

// ---------------- bf16 fragment-layout conversions ----------------
__global__ void cvt_x_frag(const float* __restrict__ x, unsigned short* __restrict__ xp) {
    int id = blockIdx.x * 256 + threadIdx.x;       // XP_ROWS*16 exact
    int n = id >> 4, ko = id & 15;
    short8 o;
    if (n < N_NODES) {
        const float4* px = (const float4*)(x + (size_t)n * C_DIM + ko * 8);
        float4 a = px[0], b = px[1];
        o[0] = (short)f2bf(a.x); o[1] = (short)f2bf(a.y);
        o[2] = (short)f2bf(a.z); o[3] = (short)f2bf(a.w);
        o[4] = (short)f2bf(b.x); o[5] = (short)f2bf(b.y);
        o[6] = (short)f2bf(b.z); o[7] = (short)f2bf(b.w);
    } else {
        o = (short8)0;
    }
    size_t off = (size_t)(n >> 4) * 2048 + (ko >> 2) * 512 + (ko & 3) * 128 + (n & 15) * 8;
    *(short8*)(xp + off) = o;
}

__global__ void cvt_w_frag(const float* __restrict__ rel_w, unsigned short* __restrict__ wf) {
    int id = blockIdx.x * 256 + threadIdx.x;       // 7*128*16 = 14336 exact
    if (id >= R_TYPES * 128 * 16) return;
    int r = id >> 11, rest = id & 2047;
    int o = rest >> 4, ko = rest & 15;
    const float4* pw = (const float4*)(rel_w + (size_t)r * 16384 + o * 128 + ko * 8);
    float4 a = pw[0], b = pw[1];
    short8 v;
    v[0] = (short)f2bf(a.x); v[1] = (short)f2bf(a.y);
    v[2] = (short)f2bf(a.z); v[3] = (short)f2bf(a.w);
    v[4] = (short)f2bf(b.x); v[5] = (short)f2bf(b.y);
    v[6] = (short)f2bf(b.z); v[7] = (short)f2bf(b.w);
    size_t off = (size_t)r * 16384 + (o >> 4) * 2048 + (ko >> 2) * 512 + (ko & 3) * 128 + (o & 15) * 8;
    *(short8*)(wf + off) = v;
}

// root_w -> MFMA B-frag layout, hi plane [0..3] and lo plane [4..7] (hi/lo bf16 split)
__global__ void cvt_rootw_frag(const float* __restrict__ root_w, unsigned short* __restrict__ wrf) {
    int id = blockIdx.x * 256 + threadIdx.x;       // 4*128*16 = 8192 exact
    if (id >= T_TYPES * 128 * 16) return;
    int t = id >> 11, rest = id & 2047;
    int o = rest >> 4, ko = rest & 15;
    const float4* pw = (const float4*)(root_w + (size_t)t * 16384 + o * 128 + ko * 8);
    float4 a = pw[0], b = pw[1];
    float v[8] = {a.x, a.y, a.z, a.w, b.x, b.y, b.z, b.w};
    short8 hi, lo;
    #pragma unroll
    for (int j = 0; j < 8; ++j) {
        unsigned short h = f2bf(v[j]);
        hi[j] = (short)h;
        lo[j] = (short)f2bf(v[j] - bf2f(h));
    }
    size_t off = (size_t)t * 16384 + (o >> 4) * 2048 + (ko >> 2) * 512 + (ko & 3) * 128 + (o & 15) * 8;
    *(short8*)(wrf + off) = hi;
    *(short8*)(wrf + (size_t)T_TYPES * 16384 + off) = lo;
}

// ---------------- root linear, NATURAL node order + local type grouping ----------
// Block = 64 consecutive nodes. LDS-group them by type into <=7 padded 16-row
// tiles (type-uniform). x reads block-contiguous; out is a pure coalesced
// OVERWRITE (bias included) -- no perm scatter, no RMW. hi/lo bf16 3-pass MFMA.
__launch_bounds__(256)
__global__ void root_nat(const float* __restrict__ x, const unsigned short* __restrict__ wrf,
                         const float* __restrict__ root_b, const int* __restrict__ tnt,
                         float* __restrict__ out) {
    __shared__ int cnt[T_TYPES];
    __shared__ int goff[T_TYPES];
    __shared__ int rankb[64];
    __shared__ int lidx[112];          // 7 tiles x 16 rows max
    __shared__ int ttyp[8];
    __shared__ int ntile_s;
    int tid = threadIdx.x;
    int base = blockIdx.x * 64;
    if (tid < T_TYPES) cnt[tid] = 0;
    if (tid < 112) lidx[tid] = -1;
    __syncthreads();
    int myt = -1;
    if (tid < 64 && base + tid < N_NODES) {
        myt = tnt[base + tid];
        rankb[tid] = atomicAdd(&cnt[myt], 1);
    }
    __syncthreads();
    if (tid == 0) {
        int s = 0;
        for (int t = 0; t < T_TYPES; ++t) {
            goff[t] = s;
            int nt = (cnt[t] + 15) >> 4;
            for (int k = 0; k < nt; ++k) ttyp[(s >> 4) + k] = t;
            s += nt << 4;
        }
        ntile_s = s >> 4;
    }
    __syncthreads();
    if (myt >= 0) lidx[goff[myt] + rankb[tid]] = base + tid;
    __syncthreads();
    int ntiles = ntile_s;

    int wave = tid >> 6, lane = tid & 63;
    int l16 = lane & 15, kq = lane >> 4;
    for (int tile = wave; tile < ntiles; tile += 4) {
        int t = ttyp[tile];
        int node = lidx[tile * 16 + l16];
        short8 ah[4], al[4];
        #pragma unroll
        for (int kb = 0; kb < 4; ++kb) {
            float v[8];
            if (node >= 0) {
                const float4* px = (const float4*)(x + (size_t)node * C_DIM + kb * 32 + kq * 8);
                float4 p0 = px[0], p1 = px[1];
                v[0] = p0.x; v[1] = p0.y; v[2] = p0.z; v[3] = p0.w;
                v[4] = p1.x; v[5] = p1.y; v[6] = p1.z; v[7] = p1.w;
            } else {
                #pragma unroll
                for (int j = 0; j < 8; ++j) v[j] = 0.0f;
            }
            #pragma unroll
            for (int j = 0; j < 8; ++j) {
                unsigned short h = f2bf(v[j]);
                ah[kb][j] = (short)h;
                al[kb][j] = (short)f2bf(v[j] - bf2f(h));
            }
        }
        const unsigned short* wh = wrf + (size_t)t * 16384;
        const unsigned short* wl = wh + (size_t)T_TYPES * 16384;
        #pragma unroll
        for (int ct = 0; ct < 8; ++ct) {
            f32x4 acc = (f32x4)0.0f;
            #pragma unroll
            for (int kb = 0; kb < 4; ++kb) {
                short8 bh = *(const short8*)(wh + ct * 2048 + kb * 512 + lane * 8);
                short8 bl = *(const short8*)(wl + ct * 2048 + kb * 512 + lane * 8);
                acc = __builtin_amdgcn_mfma_f32_16x16x32_bf16(ah[kb], bh, acc, 0, 0, 0);
                acc = __builtin_amdgcn_mfma_f32_16x16x32_bf16(al[kb], bh, acc, 0, 0, 0);
                acc = __builtin_amdgcn_mfma_f32_16x16x32_bf16(ah[kb], bl, acc, 0, 0, 0);
            }
            float bias = root_b[t * 128 + ct * 16 + l16];
            #pragma unroll
            for (int i = 0; i < 4; ++i) {
                int nr = lidx[tile * 16 + kq * 4 + i];
                if (nr >= 0)
                    out[(size_t)nr * C_DIM + ct * 16 + l16] = acc[i] + bias;   // overwrite
            }
        }
    }
}

// ---------------- fused MFMA GEMM, all 7 relations in one dispatch ----------------
__launch_bounds__(256)
__global__ void xw_gemm_all(const unsigned short* __restrict__ xp,
                            const unsigned short* __restrict__ wf,
                            unsigned short* __restrict__ xwb7) {
    int wave = threadIdx.x >> 6, lane = threadIdx.x & 63;
    int m0 = blockIdx.x * 128;

    short8 a[4][2];
    #pragma unroll
    for (int kb = 0; kb < 4; ++kb)
        #pragma unroll
        for (int rt = 0; rt < 2; ++rt) {
            size_t rtile = (size_t)blockIdx.x * 8 + wave * 2 + rt;
            a[kb][rt] = *(const short8*)(xp + rtile * 2048 + kb * 512 + lane * 8);
        }

    int col = lane & 15, rq = (lane >> 4) * 4;     // C/D: col=lane&15,row=(lane>>4)*4+i
    for (int r = 0; r < R_TYPES; ++r) {
        const unsigned short* wr = wf + (size_t)r * 16384;
        unsigned short* xwb = xwb7 + (size_t)r * XWB_PLANE;
        #pragma unroll
        for (int ct = 0; ct < 8; ++ct) {
            f32x4 acc0 = (f32x4)0.0f, acc1 = (f32x4)0.0f;
            #pragma unroll
            for (int kb = 0; kb < 4; ++kb) {
                short8 b = *(const short8*)(wr + (size_t)ct * 2048 + kb * 512 + lane * 8);
                acc0 = __builtin_amdgcn_mfma_f32_16x16x32_bf16(a[kb][0], b, acc0, 0, 0, 0);
                acc1 = __builtin_amdgcn_mfma_f32_16x16x32_bf16(a[kb][1], b, acc1, 0, 0, 0);
            }
            #pragma unroll
            for (int i = 0; i < 4; ++i) {
                int n0 = m0 + wave * 32 + rq + i;
                if (n0 < N_NODES)
                    xwb[(size_t)n0 * C_DIM + ct * 16 + col] = f2bf(acc0[i]);
                int n1 = n0 + 16;
                if (n1 < N_NODES)
                    xwb[(size_t)n1 * C_DIM + ct * 16 + col] = f2bf(acc1[i]);
            }
        }
    }
}

// fallback per-relation GEMM (single plane)
__launch_bounds__(256)
__global__ void xw_gemm_mfma(const unsigned short* __restrict__ xp,
                             const unsigned short* __restrict__ wf,
                             unsigned short* __restrict__ xwb, int r) {
    int wave = threadIdx.x >> 6, lane = threadIdx.x & 63;
    int m0 = blockIdx.x * 128;
    const unsigned short* wr = wf + (size_t)r * 16384;

    short8 a[4][2];
    #pragma unroll
    for (int kb = 0; kb < 4; ++kb)
        #pragma unroll
        for (int rt = 0; rt < 2; ++rt) {
            size_t rtile = (size_t)blockIdx.x * 8 + wave * 2 + rt;
            a[kb][rt] = *(const short8*)(xp + rtile * 2048 + kb * 512 + lane * 8);
        }

    int col = lane & 15, rq = (lane >> 4) * 4;
    #pragma unroll
    for (int ct = 0; ct < 8; ++ct) {
        f32x4 acc0 = (f32x4)0.0f, acc1 = (f32x4)0.0f;
        #pragma unroll
        for (int kb = 0; kb < 4; ++kb) {
            short8 b = *(const short8*)(wr + (size_t)ct * 2048 + kb * 512 + lane * 8);
            acc0 = __builtin_amdgcn_mfma_f32_16x16x32_bf16(a[kb][0], b, acc0, 0, 0, 0);
            acc1 = __builtin_amdgcn_mfma_f32_16x16x32_bf16(a[kb][1], b, acc1, 0, 0, 0);
        }
        #pragma unroll
        for (int i = 0; i < 4; ++i) {
            int n0 = m0 + wave * 32 + rq + i;
            if (n0 < N_NODES)
                xwb[(size_t)n0 * C_DIM + ct * 16 + col] = f2bf(acc0[i]);
            int n1 = n0 + 16;
            if (n1 < N_NODES)
                xwb[(size_t)n1 * C_DIM + ct * 16 + col] = f2bf(acc1[i]);
        }
    }
}

// ---------------- fused gather: out[d] += sum over d's edges of xwb7[r][src]*inv
// Quarter-lane layout (16 lanes x uint4 per row, 8 rows in flight), esrc pipelined.
// NOW RMW: reads the root contribution (written by root_nat) early -- latency
// hides under the edge loop -- and adds it before the final store.
__global__ void gather_fused(const int* __restrict__ dst_off, const int* __restrict__ esrc,
                             const float* __restrict__ inv,
                             const unsigned short* __restrict__ xwb7,
                             float* __restrict__ out) {
    int wave = threadIdx.x >> 6, lane = threadIdx.x & 63;
    int d = blockIdx.x * 4 + wave;
    if (d >= N_NODES) return;
    int o0 = dst_off[d], o1 = dst_off[d + 1];
    int q = lane >> 4;               // quarter: which edge of a 4-group
    int l16 = lane & 15;
    const float* invd = inv + d * R_TYPES;

    // early read of root contribution (root_nat already wrote out)
    float4 prev = make_float4(0.f, 0.f, 0.f, 0.f);
    int fidx = (l16 << 1) | q;       // meaningful for lane<32 (q in {0,1})
    if (lane < 32) prev = ((const float4*)(out + (size_t)d * C_DIM))[fidx];

    float acc[8];
    #pragma unroll
    for (int j = 0; j < 8; ++j) acc[j] = 0.f;

    int e = o0;
    int pkA = 0, pkB = 0;
    bool run = (e + 8 <= o1);
    if (run) { pkA = esrc[e + q]; pkB = esrc[e + 4 + q]; }
    while (run) {
        uint4 rA = *(const uint4*)(xwb7 + (size_t)(pkA & 0xFFFFF) * C_DIM + l16 * 8);
        uint4 rB = *(const uint4*)(xwb7 + (size_t)(pkB & 0xFFFFF) * C_DIM + l16 * 8);
        float sA = invd[pkA >> 20];
        float sB = invd[pkB >> 20];
        e += 8;
        run = (e + 8 <= o1);
        if (run) { pkA = esrc[e + q]; pkB = esrc[e + 4 + q]; }   // prefetch next iter
        acc[0] += bf2f(rA.x & 0xffffu) * sA;  acc[1] += bf2f(rA.x >> 16) * sA;
        acc[2] += bf2f(rA.y & 0xffffu) * sA;  acc[3] += bf2f(rA.y >> 16) * sA;
        acc[4] += bf2f(rA.z & 0xffffu) * sA;  acc[5] += bf2f(rA.z >> 16) * sA;
        acc[6] += bf2f(rA.w & 0xffffu) * sA;  acc[7] += bf2f(rA.w >> 16) * sA;
        acc[0] += bf2f(rB.x & 0xffffu) * sB;  acc[1] += bf2f(rB.x >> 16) * sB;
        acc[2] += bf2f(rB.y & 0xffffu) * sB;  acc[3] += bf2f(rB.y >> 16) * sB;
        acc[4] += bf2f(rB.z & 0xffffu) * sB;  acc[5] += bf2f(rB.z >> 16) * sB;
        acc[6] += bf2f(rB.w & 0xffffu) * sB;  acc[7] += bf2f(rB.w >> 16) * sB;
    }
    for (; e < o1; e += 4) {                 // tail: 1-7 edges, 1-2 groups of 4
        int idx = e + q;
        bool valid = idx < o1;
        int pk = esrc[valid ? idx : e];      // e < o1 here: safe clamp
        uint4 rw = *(const uint4*)(xwb7 + (size_t)(pk & 0xFFFFF) * C_DIM + l16 * 8);
        float s = valid ? invd[pk >> 20] : 0.0f;
        acc[0] += bf2f(rw.x & 0xffffu) * s;  acc[1] += bf2f(rw.x >> 16) * s;
        acc[2] += bf2f(rw.y & 0xffffu) * s;  acc[3] += bf2f(rw.y >> 16) * s;
        acc[4] += bf2f(rw.z & 0xffffu) * s;  acc[5] += bf2f(rw.z >> 16) * s;
        acc[6] += bf2f(rw.w & 0xffffu) * s;  acc[7] += bf2f(rw.w >> 16) * s;
    }

    #pragma unroll
    for (int j = 0; j < 8; ++j) {
        acc[j] += __shfl_xor(acc[j], 16);
        acc[j] += __shfl_xor(acc[j], 32);
    }
    if (lane < 32) {
        float4 w;
        if (lane < 16)
            w = make_float4(acc[0] + prev.x, acc[1] + prev.y, acc[2] + prev.z, acc[3] + prev.w);
        else
            w = make_float4(acc[4] + prev.x, acc[5] + prev.y, acc[6] + prev.z, acc[7] + prev.w);
        ((float4*)(out + (size_t)d * C_DIM))[fidx] = w;
    }
}

// ---------------- fallback gather (single xwb plane, filter by r, RMW out) -----
__global__ void gather_rel_f(const int* __restrict__ dst_off, const int* __restrict__ esrc,
                             const float* __restrict__ inv,
                             const unsigned short* __restrict__ xwb,
                             float* __restrict__ out, int rf) {
    int wave = threadIdx.x >> 6, lane = threadIdx.x & 63;
    int d = blockIdx.x * 4 + wave;
    if (d >= N_NODES) return;
    int o0 = dst_off[d], o1 = dst_off[d + 1];
    float ax = 0.0f, ay = 0.0f;
    bool any = false;
    for (int e = o0; e < o1; ++e) {
        int pk = esrc[e];
        if ((pk >> 20) != rf) continue;
        any = true;
        int src = (pk & 0xFFFFF) - rf * XP_ROWS;
        unsigned int row = *(const unsigned int*)(xwb + (size_t)src * C_DIM + lane * 2);
        ax += bf2f(row & 0xffffu);
        ay += bf2f(row >> 16);
    }
    if (!any) return;
    float sc = inv[d * R_TYPES + rf];
    float2* po = (float2*)(out + (size_t)d * C_DIM) + lane;
    float2 v = *po;
    v.x += ax * sc;
    v.y += ay * sc;
    *po = v;
}

extern "C" void kernel_launch(void* const* d_in, const int* in_sizes, int n_in,
                              void* d_out, int out_size, void* d_ws, size_t ws_size,
                              hipStream_t stream) {
    const float* x      = (const float*)d_in[0];
    const int*   ei     = (const int*)d_in[1];
    const int*   et     = (const int*)d_in[2];
    const int*   tnt    = (const int*)d_in[3];
    const float* rel_w  = (const float*)d_in[4];
    const float* root_w = (const float*)d_in[5];
    const float* root_b = (const float*)d_in[6];
    float* out = (float*)d_out;

    char* ws = (char*)d_ws;
    int*   cnti    = (int*)(ws + OFF_CNTI);
    float* inv     = (float*)(ws + OFF_INV);
    int*   dst_off = (int*)(ws + OFF_DOFF);
    int*   cursor  = (int*)(ws + OFF_CURS);
    int*   bsum    = (int*)(ws + OFF_BSUM);
    int*   esrc    = (int*)(ws + OFF_ESRC);
    unsigned short* xp  = (unsigned short*)(ws + OFF_XP);
    unsigned short* wf  = (unsigned short*)(ws + OFF_WF);
    unsigned short* xwb = (unsigned short*)(ws + OFF_XWB);
    unsigned short* wrf = (unsigned short*)(ws + OFF_WRF);   // in old perm region

    const bool full = (ws_size >= FULL_NEED);   // constant across calls: graph-safe

    hipMemsetAsync(ws + OFF_CNTI, 0, SEGS * sizeof(int), stream);

    // root linear first: writes ALL of out (bias included); gather then RMWs.
    cvt_rootw_frag<<<32, 256, 0, stream>>>(root_w, wrf);
    root_nat<<<NB_ROOT, 256, 0, stream>>>(x, wrf, root_b, tnt, out);

    // dst-CSR sort of edges
    edge_hist  <<<NB_E, 256, 0, stream>>>(ei, et, cnti);
    inv_kernel <<<(SEGS + 255) / 256, 256, 0, stream>>>(cnti, inv);
    dst_scan1  <<<NB_N, 256, 0, stream>>>(cnti, dst_off, bsum);
    seg_scan2  <<<1, 256, 0, stream>>>(bsum, NB_N);
    dst_scan3  <<<NB_N, 256, 0, stream>>>(dst_off, cursor, bsum);
    place_edges<<<NB_E * 8, 256, 0, stream>>>(ei, et, cursor, esrc);

    // bf16 fragment-layout conversions
    cvt_x_frag<<<(XP_ROWS * 16) / 256, 256, 0, stream>>>(x, xp);
    cvt_w_frag<<<56, 256, 0, stream>>>(rel_w, wf);

    if (full) {
        xw_gemm_all <<<XP_ROWS / 128, 256, 0, stream>>>(xp, wf, xwb);
        gather_fused<<<(N_NODES + 3) / 4, 256, 0, stream>>>(dst_off, esrc, inv, xwb, out);
    } else {
        for (int r = 0; r < R_TYPES; ++r) {
            xw_gemm_mfma<<<XP_ROWS / 128, 256, 0, stream>>>(xp, wf, xwb, r);
            gather_rel_f<<<(N_NODES + 3) / 4, 256, 0, stream>>>(dst_off, esrc, inv, xwb, out, r);
        }
    }
}